// Round 7
// baseline (118.941 us; speedup 1.0000x reference)
//
#include <hip/hip_runtime.h>

#define NB 64
#define NT 1024
#define NA 512
#define NF 32
#define KW 31
#define PADW 15
#define TB 32
#define CWN (2 * KW * NF)   // 1984 floats of transposed conv weights

typedef __fp16 half2v __attribute__((ext_vector_type(2)));

__device__ __forceinline__ float fast_tanh(float x) {
    float e = __builtin_amdgcn_exp2f(x * 2.885390081777927f);
    return 1.0f - 2.0f * __builtin_amdgcn_rcpf(1.0f + e);
}
__device__ __forceinline__ float fast_sigmoid(float u) {
    return __builtin_amdgcn_rcpf(1.0f + __builtin_amdgcn_exp2f(-u * 1.4426950408889634f));
}
__device__ __forceinline__ unsigned pkrtz(float a, float b) {
    half2v h = __builtin_amdgcn_cvt_pkrtz(a, b);
    return __builtin_bit_cast(unsigned, h);
}
__device__ __forceinline__ float fdot2u(unsigned cv, unsigned lw, float acc) {
#if __has_builtin(__builtin_amdgcn_fdot2)
    return __builtin_amdgcn_fdot2(__builtin_bit_cast(half2v, cv),
                                  __builtin_bit_cast(half2v, lw), acc, false);
#else
    half2v a = __builtin_bit_cast(half2v, cv), b = __builtin_bit_cast(half2v, lw);
    return acc + (float)a.x * (float)b.x + (float)a.y * (float)b.y;
#endif
}

// ---------------- kernel A: pq = query @ W_w^T + W_b ; block 0 also transposes conv_w
__global__ __launch_bounds__(256) void lsa_pq(
    const float* __restrict__ query, const float* __restrict__ Ww,
    const float* __restrict__ Wb, const float* __restrict__ convw,
    float* __restrict__ pq, float* __restrict__ cwT)
{
    if (blockIdx.x == 0) {
        for (int i = threadIdx.x; i < NF * 2 * KW; i += 256) {
            int f = i / (2 * KW);
            int r = i - f * 2 * KW;
            int c = r / KW;
            int k = r - c * KW;
            cwT[(c * KW + k) * NF + f] = convw[i];   // [c][k][f]
        }
    }
    __shared__ float qs[NA];
    int tid = threadIdx.x;
    int b = blockIdx.x >> 1;
    int a0 = (blockIdx.x & 1) * 256;
    qs[tid]       = query[b * NA + tid];
    qs[tid + 256] = query[b * NA + tid + 256];
    __syncthreads();
    int a = a0 + tid;
    const float4* wr = (const float4*)(Ww + (long)a * NA);
    float acc  = Wb[a];
    float acc2 = 0.f;
#pragma unroll 8
    for (int k = 0; k < NA / 4; ++k) {
        float4 w = wr[k];
        float4 q4 = *(const float4*)(qs + 4 * k);
        acc  += w.x * q4.x + w.y * q4.y;
        acc2 += w.z * q4.z + w.w * q4.w;
    }
    pq[b * NA + a] = acc + acc2;
}

// ---------------- kernel B (hot): s = sigmoid(u) -> d_out
// 4 waves: wave = (a-half, t-half). Thread owns 4 consecutive a's x 16 tt.
__global__ __launch_bounds__(256, 3) void lsa_main(
    const float* __restrict__ enc, const float* __restrict__ cum,
    const float* __restrict__ att, const float* __restrict__ cwT,
    const float* __restrict__ Lw, const float* __restrict__ Lb,
    const float* __restrict__ vw, const float* __restrict__ pq,
    float* __restrict__ sout)
{
    __shared__ float cw_s[CWN];            // conv weights [c][k][f], 7.75 KB
    __shared__ float cum_s[TB + 30];
    __shared__ float att_s[TB + 30];
    __shared__ unsigned cvsh[TB][20];      // f16x2 conv output, 80B row stride (16B-mult)
    __shared__ float wred[2][33];

    int tid  = threadIdx.x;
    int lane = tid & 63;
    int wv   = tid >> 6;
    int b    = blockIdx.x >> 5;
    int t0   = (blockIdx.x & 31) * TB;

    int ah = wv >> 1;                      // a-half: 0 -> a 0..255, 1 -> 256..511
    int th = wv & 1;                       // t-half: 0 -> tt 0..15, 1 -> 16..31
    int a0 = ah * 256 + 4 * lane;          // 4 consecutive a's per thread

    // ---- stage conv weights into LDS (coalesced float4 copy)
    {
        const float4* src = (const float4*)cwT;
        float4* dst = (float4*)cw_s;
        if (tid < 248) {                   // 496 float4 total
            dst[tid]       = src[tid];
            dst[tid + 248] = src[tid + 248];
        }
    }
    // ---- stage cum/att slice (with halo)
    if (tid < TB + 30) {
        int t = t0 - PADW + tid;
        bool ok = (t >= 0) && (t < NT);
        cum_s[tid] = ok ? cum[b * NT + t] : 0.f;
        att_s[tid] = ok ? att[b * NT + t] : 0.f;
    }

    // ---- pack this thread's 4 L_w rows to f16x2 registers (64 VGPRs)
    unsigned h0[16], h1[16], h2[16], h3[16];
    {
        const float4* l0 = (const float4*)(Lw + (long)(a0 + 0) * NF);
        const float4* l1 = (const float4*)(Lw + (long)(a0 + 1) * NF);
        const float4* l2 = (const float4*)(Lw + (long)(a0 + 2) * NF);
        const float4* l3 = (const float4*)(Lw + (long)(a0 + 3) * NF);
#pragma unroll
        for (int q = 0; q < 8; ++q) {
            float4 w0 = l0[q], w1 = l1[q], w2 = l2[q], w3 = l3[q];
            h0[2 * q] = pkrtz(w0.x, w0.y); h0[2 * q + 1] = pkrtz(w0.z, w0.w);
            h1[2 * q] = pkrtz(w1.x, w1.y); h1[2 * q + 1] = pkrtz(w1.z, w1.w);
            h2[2 * q] = pkrtz(w2.x, w2.y); h2[2 * q + 1] = pkrtz(w2.z, w2.w);
            h3[2 * q] = pkrtz(w3.x, w3.y); h3[2 * q + 1] = pkrtz(w3.z, w3.w);
        }
    }
    float4 c4 = *(const float4*)(pq + b * NA + a0);
    {
        float4 lb4 = *(const float4*)(Lb + a0);
        c4.x += lb4.x; c4.y += lb4.y; c4.z += lb4.z; c4.w += lb4.w;
    }
    float4 v4 = *(const float4*)(vw + a0);
    __syncthreads();

    // ---- conv phase: wave wv computes filters [8wv, 8wv+8) for tt = lane&31
    //      weights from LDS as broadcast b128 reads (no scalar-load stalls)
    {
        int tt  = lane & 31;
        int fbu = wv * 8;
        float acc[8] = {0, 0, 0, 0, 0, 0, 0, 0};
#pragma unroll
        for (int k = 0; k < KW; ++k) {
            float x0 = cum_s[tt + k];
            float x1 = att_s[tt + k];
            const float4* A  = (const float4*)(cw_s + k * NF + fbu);
            const float4* Bv = (const float4*)(cw_s + (KW + k) * NF + fbu);
#pragma unroll
            for (int j = 0; j < 2; ++j) {
                float4 wa = A[j], wb = Bv[j];
                acc[4 * j + 0] = fmaf(x0, wa.x, fmaf(x1, wb.x, acc[4 * j + 0]));
                acc[4 * j + 1] = fmaf(x0, wa.y, fmaf(x1, wb.y, acc[4 * j + 1]));
                acc[4 * j + 2] = fmaf(x0, wa.z, fmaf(x1, wb.z, acc[4 * j + 2]));
                acc[4 * j + 3] = fmaf(x0, wa.w, fmaf(x1, wb.w, acc[4 * j + 3]));
            }
        }
        if (lane < 32) {
            uint4 pk;
            pk.x = pkrtz(acc[0], acc[1]);
            pk.y = pkrtz(acc[2], acc[3]);
            pk.z = pkrtz(acc[4], acc[5]);
            pk.w = pkrtz(acc[6], acc[7]);
            *(uint4*)&cvsh[tt][fbu >> 1] = pk;
        }
    }
    __syncthreads();

#define DOROW(hr, cinit, vmul)                                      \
    {                                                               \
        float ya = (cinit), yb = 0.f;                               \
        ya = fdot2u(cva.x, hr[0],  ya); yb = fdot2u(cva.y, hr[1],  yb); \
        ya = fdot2u(cva.z, hr[2],  ya); yb = fdot2u(cva.w, hr[3],  yb); \
        ya = fdot2u(cvb.x, hr[4],  ya); yb = fdot2u(cvb.y, hr[5],  yb); \
        ya = fdot2u(cvb.z, hr[6],  ya); yb = fdot2u(cvb.w, hr[7],  yb); \
        ya = fdot2u(cvc.x, hr[8],  ya); yb = fdot2u(cvc.y, hr[9],  yb); \
        ya = fdot2u(cvc.z, hr[10], ya); yb = fdot2u(cvc.w, hr[11], yb); \
        ya = fdot2u(cvd.x, hr[12], ya); yb = fdot2u(cvd.y, hr[13], yb); \
        ya = fdot2u(cvd.z, hr[14], ya); yb = fdot2u(cvd.w, hr[15], yb); \
        s = fmaf(fast_tanh(ya + yb), (vmul), s);                    \
    }

    // ---- main loop: 16 tt (this wave's t-half), 4 a's per thread
    float p[16];
    const float* erow = enc + ((long)b * NT + t0 + th * 16) * NA + a0;
#pragma unroll
    for (int tt = 0; tt < 16; ++tt) {
        int gtt = th * 16 + tt;
        float4 e = *(const float4*)(erow + (long)tt * NA);
        uint4 cva = *(const uint4*)&cvsh[gtt][0];
        uint4 cvb = *(const uint4*)&cvsh[gtt][4];
        uint4 cvc = *(const uint4*)&cvsh[gtt][8];
        uint4 cvd = *(const uint4*)&cvsh[gtt][12];
        float s = 0.f;
        DOROW(h0, c4.x + e.x, v4.x);
        DOROW(h1, c4.y + e.y, v4.y);
        DOROW(h2, c4.z + e.z, v4.z);
        DOROW(h3, c4.w + e.w, v4.w);
        p[tt] = s;
    }
#undef DOROW

    // ---- register butterfly transpose-reduce (len 16 across lane bits 0..3)
    {
        int len = 16;
#pragma unroll
        for (int m = 1; m <= 8; m <<= 1) {
            int half = len >> 1;
            bool up = (lane & m) != 0;
#pragma unroll
            for (int i = 0; i < 8; ++i) {
                if (i < half) {
                    float send = up ? p[i] : p[i + half];
                    float keep = up ? p[i + half] : p[i];
                    p[i] = keep + __shfl_xor(send, m, 64);
                }
            }
            len = half;
        }
        float v = p[0] + __shfl_xor(p[0], 16, 64);
        v = v + __shfl_xor(v, 32, 64);
        int l4 = lane & 15;
        int tt = ((l4 & 1) << 3) | ((l4 & 2) << 1) | ((l4 & 4) >> 1) | ((l4 & 8) >> 3);
        if (lane < 16) wred[ah][th * 16 + tt] = v;
    }
    __syncthreads();
    if (tid < 32) {
        float u = wred[0][tid] + wred[1][tid];
        sout[b * NT + t0 + tid] = fast_sigmoid(u);
    }
}

// ---------------- kernel C: normalize with alpha recursion + mask (in place)
__global__ __launch_bounds__(256) void lsa_norm(
    const float* __restrict__ alpha, const int* __restrict__ plen,
    float* __restrict__ out)
{
    __shared__ float red[4];
    int tid = threadIdx.x;
    int b = blockIdx.x;
    int pl = plen[b];
    float w[4];
    float psum = 0.f;
#pragma unroll
    for (int j = 0; j < 4; ++j) {
        int t = tid + 256 * j;
        float s   = out[b * NT + t];
        float al  = alpha[b * NT + t];
        float am1 = (t >= 1) ? alpha[b * NT + t - 1] : 0.f;
        float am2 = (t >= 2) ? alpha[b * NT + t - 2] : 0.f;
        float val = (t < pl) ? (al + am1 + am2 + 1e-7f) * s : 0.f;
        w[j] = val;
        psum += val;
    }
#pragma unroll
    for (int m = 32; m >= 1; m >>= 1) psum += __shfl_xor(psum, m, 64);
    int lane = tid & 63, wid = tid >> 6;
    if (lane == 0) red[wid] = psum;
    __syncthreads();
    float total = red[0] + red[1] + red[2] + red[3];
    float inv = 1.0f / total;
#pragma unroll
    for (int j = 0; j < 4; ++j) {
        int t = tid + 256 * j;
        out[b * NT + t] = w[j] * inv;
    }
}

extern "C" void kernel_launch(void* const* d_in, const int* in_sizes, int n_in,
                              void* d_out, int out_size, void* d_ws, size_t ws_size,
                              hipStream_t stream)
{
    const float* enc   = (const float*)d_in[0];
    const float* query = (const float*)d_in[1];
    const float* cum   = (const float*)d_in[2];
    const float* att   = (const float*)d_in[3];
    const float* alpha = (const float*)d_in[4];
    const float* convw = (const float*)d_in[5];
    const float* Lw    = (const float*)d_in[6];
    const float* Lb    = (const float*)d_in[7];
    const float* Ww    = (const float*)d_in[8];
    const float* Wb    = (const float*)d_in[9];
    const float* vw    = (const float*)d_in[10];
    const int*   plen  = (const int*)d_in[12];

    float* pq  = (float*)d_ws;                       // 64*512 floats = 128 KB
    float* cwT = (float*)d_ws + NB * NA;             // 1984 floats
    float* sout = (float*)d_out;

    lsa_pq  <<<NB * 2,         256, 0, stream>>>(query, Ww, Wb, convw, pq, cwT);
    lsa_main<<<NB * (NT / TB), 256, 0, stream>>>(enc, cum, att, cwT, Lw, Lb, vw, pq, sout);
    lsa_norm<<<NB,             256, 0, stream>>>(alpha, plen, sout);
}

// Round 8
// 63.722 us; speedup vs baseline: 1.8666x; 1.8666x over previous
//
#include <hip/hip_runtime.h>

#define NB 64
#define NT 1024
#define NA 512
#define NF 32
#define KW 31
#define PADW 15
#define TC 64                      // t's per block
#define CWN (2 * KW * NF)          // 1984 floats of transposed conv weights

typedef __fp16 half2v __attribute__((ext_vector_type(2)));

__device__ __forceinline__ float fast_tanh(float x) {
    float e = __builtin_amdgcn_exp2f(x * 2.885390081777927f);
    return 1.0f - 2.0f * __builtin_amdgcn_rcpf(1.0f + e);
}
__device__ __forceinline__ float fast_sigmoid(float u) {
    return __builtin_amdgcn_rcpf(1.0f + __builtin_amdgcn_exp2f(-u * 1.4426950408889634f));
}
__device__ __forceinline__ unsigned pkrtz(float a, float b) {
    half2v h = __builtin_amdgcn_cvt_pkrtz(a, b);
    return __builtin_bit_cast(unsigned, h);
}
__device__ __forceinline__ float fdot2u(unsigned cv, unsigned lw, float acc) {
#if __has_builtin(__builtin_amdgcn_fdot2)
    return __builtin_amdgcn_fdot2(__builtin_bit_cast(half2v, cv),
                                  __builtin_bit_cast(half2v, lw), acc, false);
#else
    half2v a = __builtin_bit_cast(half2v, cv), b = __builtin_bit_cast(half2v, lw);
    return acc + (float)a.x * (float)b.x + (float)a.y * (float)b.y;
#endif
}

// ---------------- kernel A: pq = query @ W_w^T + W_b ; block 0 also transposes conv_w
__global__ __launch_bounds__(256) void lsa_pq(
    const float* __restrict__ query, const float* __restrict__ Ww,
    const float* __restrict__ Wb, const float* __restrict__ convw,
    float* __restrict__ pq, float* __restrict__ cwT)
{
    if (blockIdx.x == 0) {
        for (int i = threadIdx.x; i < NF * 2 * KW; i += 256) {
            int f = i / (2 * KW);
            int r = i - f * 2 * KW;
            int c = r / KW;
            int k = r - c * KW;
            cwT[(c * KW + k) * NF + f] = convw[i];   // [c][k][f]
        }
    }
    __shared__ float qs[NA];
    int tid = threadIdx.x;
    int b = blockIdx.x >> 1;
    int a0 = (blockIdx.x & 1) * 256;
    qs[tid]       = query[b * NA + tid];
    qs[tid + 256] = query[b * NA + tid + 256];
    __syncthreads();
    int a = a0 + tid;
    const float4* wr = (const float4*)(Ww + (long)a * NA);
    float acc  = Wb[a];
    float acc2 = 0.f;
#pragma unroll 8
    for (int k = 0; k < NA / 4; ++k) {
        float4 w = wr[k];
        float4 q4 = *(const float4*)(qs + 4 * k);
        acc  += w.x * q4.x + w.y * q4.y;
        acc2 += w.z * q4.z + w.w * q4.w;
    }
    pq[b * NA + a] = acc + acc2;
}

// ---------------- kernel B (hot): s = sigmoid(u) -> d_out
// 1024 blocks = 4/CU fully resident. Thread owns a = 2*tid, 2*tid+1 for 64 t's.
__global__ __launch_bounds__(256, 4) void lsa_main(
    const float* __restrict__ enc, const float* __restrict__ cum,
    const float* __restrict__ att, const float* __restrict__ cwT,
    const float* __restrict__ Lw, const float* __restrict__ Lb,
    const float* __restrict__ vw, const float* __restrict__ pq,
    float* __restrict__ sout)
{
    __shared__ float cw_s[CWN];            // conv weights [c][k][f], 7.75 KB
    __shared__ float cum_s[TC + 30];
    __shared__ float att_s[TC + 30];
    __shared__ unsigned cvsh[TC][20];      // f16x2 conv output, 80B row stride
    __shared__ float wred[4][TC + 2];      // per-wave tt sums

    int tid  = threadIdx.x;
    int lane = tid & 63;
    int wv   = tid >> 6;
    int b    = blockIdx.x >> 4;            // NT/TC = 16 chunks
    int t0   = (blockIdx.x & 15) * TC;

    // ---- stage conv weights into LDS (coalesced float4 copy)
    {
        const float4* src = (const float4*)cwT;
        float4* dst = (float4*)cw_s;
        if (tid < 248) {                   // 496 float4 total
            dst[tid]       = src[tid];
            dst[tid + 248] = src[tid + 248];
        }
    }
    // ---- stage cum/att slice (with halo)
    if (tid < TC + 30) {
        int t = t0 - PADW + tid;
        bool ok = (t >= 0) && (t < NT);
        cum_s[tid] = ok ? cum[b * NT + t] : 0.f;
        att_s[tid] = ok ? att[b * NT + t] : 0.f;
    }

    // ---- per-thread constants
    int a0 = 2 * tid;
    const float4* lp = (const float4*)(Lw + (long)a0 * NF);
    float4 lf[16];
#pragma unroll
    for (int i = 0; i < 16; ++i) lf[i] = lp[i];
    float c0 = pq[b * NA + a0]     + Lb[a0];
    float c1 = pq[b * NA + a0 + 1] + Lb[a0 + 1];
    float vx = vw[a0], vy = vw[a0 + 1];

    unsigned h0[16], h1[16];
#pragma unroll
    for (int i = 0; i < 8; ++i) {
        h0[2 * i]     = pkrtz(lf[i].x, lf[i].y);
        h0[2 * i + 1] = pkrtz(lf[i].z, lf[i].w);
        h1[2 * i]     = pkrtz(lf[8 + i].x, lf[8 + i].y);
        h1[2 * i + 1] = pkrtz(lf[8 + i].z, lf[8 + i].w);
    }
    __syncthreads();

    // ---- conv phase: wave wv computes filters [8wv, 8wv+8) for tt = lane (all 64)
    //      weights from LDS as broadcast b128 reads (no scalar-load stalls)
    {
        int tt  = lane;
        int fbu = wv * 8;
        float acc[8] = {0, 0, 0, 0, 0, 0, 0, 0};
#pragma unroll
        for (int k = 0; k < KW; ++k) {
            float x0 = cum_s[tt + k];
            float x1 = att_s[tt + k];
            const float4* A  = (const float4*)(cw_s + k * NF + fbu);
            const float4* Bv = (const float4*)(cw_s + (KW + k) * NF + fbu);
#pragma unroll
            for (int j = 0; j < 2; ++j) {
                float4 wa = A[j], wb = Bv[j];
                acc[4 * j + 0] = fmaf(x0, wa.x, fmaf(x1, wb.x, acc[4 * j + 0]));
                acc[4 * j + 1] = fmaf(x0, wa.y, fmaf(x1, wb.y, acc[4 * j + 1]));
                acc[4 * j + 2] = fmaf(x0, wa.z, fmaf(x1, wb.z, acc[4 * j + 2]));
                acc[4 * j + 3] = fmaf(x0, wa.w, fmaf(x1, wb.w, acc[4 * j + 3]));
            }
        }
        uint4 pk;
        pk.x = pkrtz(acc[0], acc[1]);
        pk.y = pkrtz(acc[2], acc[3]);
        pk.z = pkrtz(acc[4], acc[5]);
        pk.w = pkrtz(acc[6], acc[7]);
        *(uint4*)&cvsh[tt][wv * 4] = pk;
    }
    __syncthreads();

    // ---- main loop: two passes of 32 tt; per-thread 2 a's; f16 dot2
    const float* erow = enc + ((long)b * NT + t0) * NA + a0;
#pragma unroll 1
    for (int half = 0; half < 2; ++half) {
        float p32[32];
#pragma unroll
        for (int tt = 0; tt < 32; ++tt) {
            int gtt = half * 32 + tt;
            float2 e = *(const float2*)(erow + (long)gtt * NA);
            float x0[2] = {c0 + e.x, 0.f};
            float x1[2] = {c1 + e.y, 0.f};
#pragma unroll
            for (int q = 0; q < 4; ++q) {
                uint4 cv = *(const uint4*)&cvsh[gtt][4 * q];
                int p = q & 1;
                x0[p] = fdot2u(cv.x, h0[4 * q + 0], x0[p]);
                x0[p] = fdot2u(cv.y, h0[4 * q + 1], x0[p]);
                x0[p] = fdot2u(cv.z, h0[4 * q + 2], x0[p]);
                x0[p] = fdot2u(cv.w, h0[4 * q + 3], x0[p]);
                x1[p] = fdot2u(cv.x, h1[4 * q + 0], x1[p]);
                x1[p] = fdot2u(cv.y, h1[4 * q + 1], x1[p]);
                x1[p] = fdot2u(cv.z, h1[4 * q + 2], x1[p]);
                x1[p] = fdot2u(cv.w, h1[4 * q + 3], x1[p]);
            }
            p32[tt] = fast_tanh(x0[0] + x0[1]) * vx + fast_tanh(x1[0] + x1[1]) * vy;
        }

        // register butterfly transpose-reduce across lane bits 0..4
        {
            int len = 32;
#pragma unroll
            for (int m = 1; m <= 16; m <<= 1) {
                int hlen = len >> 1;
                bool up = (lane & m) != 0;
#pragma unroll
                for (int i = 0; i < 16; ++i) {
                    if (i < hlen) {
                        float send = up ? p32[i] : p32[i + hlen];
                        float keep = up ? p32[i + hlen] : p32[i];
                        p32[i] = keep + __shfl_xor(send, m, 64);
                    }
                }
                len = hlen;
            }
            float v = p32[0] + __shfl_xor(p32[0], 32, 64);
            int l = lane & 31;
            int tt = ((l & 1) << 4) | ((l & 2) << 2) | (l & 4) | ((l & 8) >> 2) | ((l & 16) >> 4);
            if (lane < 32) wred[wv][half * 32 + tt] = v;
        }
    }
    __syncthreads();
    if (tid < TC) {
        float u = wred[0][tid] + wred[1][tid] + wred[2][tid] + wred[3][tid];
        sout[b * NT + t0 + tid] = fast_sigmoid(u);
    }
}

// ---------------- kernel C: normalize with alpha recursion + mask (in place)
__global__ __launch_bounds__(256) void lsa_norm(
    const float* __restrict__ alpha, const int* __restrict__ plen,
    float* __restrict__ out)
{
    __shared__ float red[4];
    int tid = threadIdx.x;
    int b = blockIdx.x;
    int pl = plen[b];
    float w[4];
    float psum = 0.f;
#pragma unroll
    for (int j = 0; j < 4; ++j) {
        int t = tid + 256 * j;
        float s   = out[b * NT + t];
        float al  = alpha[b * NT + t];
        float am1 = (t >= 1) ? alpha[b * NT + t - 1] : 0.f;
        float am2 = (t >= 2) ? alpha[b * NT + t - 2] : 0.f;
        float val = (t < pl) ? (al + am1 + am2 + 1e-7f) * s : 0.f;
        w[j] = val;
        psum += val;
    }
#pragma unroll
    for (int m = 32; m >= 1; m >>= 1) psum += __shfl_xor(psum, m, 64);
    int lane = tid & 63, wid = tid >> 6;
    if (lane == 0) red[wid] = psum;
    __syncthreads();
    float total = red[0] + red[1] + red[2] + red[3];
    float inv = 1.0f / total;
#pragma unroll
    for (int j = 0; j < 4; ++j) {
        int t = tid + 256 * j;
        out[b * NT + t] = w[j] * inv;
    }
}

extern "C" void kernel_launch(void* const* d_in, const int* in_sizes, int n_in,
                              void* d_out, int out_size, void* d_ws, size_t ws_size,
                              hipStream_t stream)
{
    const float* enc   = (const float*)d_in[0];
    const float* query = (const float*)d_in[1];
    const float* cum   = (const float*)d_in[2];
    const float* att   = (const float*)d_in[3];
    const float* alpha = (const float*)d_in[4];
    const float* convw = (const float*)d_in[5];
    const float* Lw    = (const float*)d_in[6];
    const float* Lb    = (const float*)d_in[7];
    const float* Ww    = (const float*)d_in[8];
    const float* Wb    = (const float*)d_in[9];
    const float* vw    = (const float*)d_in[10];
    const int*   plen  = (const int*)d_in[12];

    float* pq  = (float*)d_ws;                       // 64*512 floats = 128 KB
    float* cwT = (float*)d_ws + NB * NA;             // 1984 floats
    float* sout = (float*)d_out;

    lsa_pq  <<<NB * 2,         256, 0, stream>>>(query, Ww, Wb, convw, pq, cwT);
    lsa_main<<<NB * (NT / TC), 256, 0, stream>>>(enc, cum, att, cwT, Lw, Lb, vw, pq, sout);
    lsa_norm<<<NB,             256, 0, stream>>>(alpha, plen, sout);
}

// Round 9
// 56.540 us; speedup vs baseline: 2.1037x; 1.1270x over previous
//
#include <hip/hip_runtime.h>

#define NB 64
#define NT 1024
#define NA 512
#define NF 32
#define KW 31
#define PADW 15
#define TC 64                      // t's per block
#define CWN (2 * KW * NF)          // 1984 floats of transposed conv weights

typedef __fp16 half2v __attribute__((ext_vector_type(2)));

__device__ __forceinline__ float fast_tanh(float x) {
    float e = __builtin_amdgcn_exp2f(x * 2.885390081777927f);
    return 1.0f - 2.0f * __builtin_amdgcn_rcpf(1.0f + e);
}
__device__ __forceinline__ float fast_sigmoid(float u) {
    return __builtin_amdgcn_rcpf(1.0f + __builtin_amdgcn_exp2f(-u * 1.4426950408889634f));
}
__device__ __forceinline__ unsigned pkrtz(float a, float b) {
    half2v h = __builtin_amdgcn_cvt_pkrtz(a, b);
    return __builtin_bit_cast(unsigned, h);
}
__device__ __forceinline__ float fdot2u(unsigned cv, unsigned lw, float acc) {
#if __has_builtin(__builtin_amdgcn_fdot2)
    return __builtin_amdgcn_fdot2(__builtin_bit_cast(half2v, cv),
                                  __builtin_bit_cast(half2v, lw), acc, false);
#else
    half2v a = __builtin_bit_cast(half2v, cv), b = __builtin_bit_cast(half2v, lw);
    return acc + (float)a.x * (float)b.x + (float)a.y * (float)b.y;
#endif
}

// ---------------- kernel A: pq = query @ W_w^T + W_b (coalesced row-per-wave GEMV)
// grid = NB * 8 blocks; block = (b, 64-a chunk); wave owns 16 rows.
// Lane l reads Ww[a][8l..8l+7] -> the wave reads the full contiguous 2 KB row.
__global__ __launch_bounds__(256) void lsa_pq(
    const float* __restrict__ query, const float* __restrict__ Ww,
    const float* __restrict__ Wb, const float* __restrict__ convw,
    float* __restrict__ pq, float* __restrict__ cwT)
{
    if (blockIdx.x == 0) {
        for (int i = threadIdx.x; i < NF * 2 * KW; i += 256) {
            int f = i / (2 * KW);
            int r = i - f * 2 * KW;
            int c = r / KW;
            int k = r - c * KW;
            cwT[(c * KW + k) * NF + f] = convw[i];   // [c][k][f]
        }
    }
    __shared__ float qs[NA];
    int tid  = threadIdx.x;
    int lane = tid & 63;
    int wv   = tid >> 6;
    int b     = blockIdx.x >> 3;
    int chunk = blockIdx.x & 7;              // 64-a chunk
    qs[tid]       = query[b * NA + tid];
    qs[tid + 256] = query[b * NA + tid + 256];
    __syncthreads();

    float4 q0 = *(const float4*)(qs + 8 * lane);
    float4 q1 = *(const float4*)(qs + 8 * lane + 4);
#pragma unroll 4
    for (int i = 0; i < 16; ++i) {
        int a = chunk * 64 + wv * 16 + i;
        const float4* wr = (const float4*)(Ww + (long)a * NA + 8 * lane);
        float4 w0 = wr[0], w1 = wr[1];
        float s = w0.x * q0.x + w0.y * q0.y + w0.z * q0.z + w0.w * q0.w
                + w1.x * q1.x + w1.y * q1.y + w1.z * q1.z + w1.w * q1.w;
#pragma unroll
        for (int m = 1; m <= 32; m <<= 1) s += __shfl_xor(s, m, 64);
        if (lane == 0) pq[b * NA + a] = s + Wb[a];
    }
}

// ---------------- kernel B (hot): s = sigmoid(u) -> d_out
// 1024 blocks = 4/CU fully resident. Thread owns a = 2*tid, 2*tid+1 for 64 t's.
__global__ __launch_bounds__(256, 4) void lsa_main(
    const float* __restrict__ enc, const float* __restrict__ cum,
    const float* __restrict__ att, const float* __restrict__ cwT,
    const float* __restrict__ Lw, const float* __restrict__ Lb,
    const float* __restrict__ vw, const float* __restrict__ pq,
    float* __restrict__ sout)
{
    __shared__ float cw_s[CWN];            // conv weights [c][k][f], 7.75 KB
    __shared__ float cum_s[TC + 30];
    __shared__ float att_s[TC + 30];
    __shared__ unsigned cvsh[TC][20];      // f16x2 conv output, 80B row stride
    __shared__ float wred[4][TC + 2];      // per-wave tt sums

    int tid  = threadIdx.x;
    int lane = tid & 63;
    int wv   = tid >> 6;
    int b    = blockIdx.x >> 4;            // NT/TC = 16 chunks
    int t0   = (blockIdx.x & 15) * TC;

    // ---- stage conv weights into LDS (coalesced float4 copy)
    {
        const float4* src = (const float4*)cwT;
        float4* dst = (float4*)cw_s;
        if (tid < 248) {                   // 496 float4 total
            dst[tid]       = src[tid];
            dst[tid + 248] = src[tid + 248];
        }
    }
    // ---- stage cum/att slice (with halo)
    if (tid < TC + 30) {
        int t = t0 - PADW + tid;
        bool ok = (t >= 0) && (t < NT);
        cum_s[tid] = ok ? cum[b * NT + t] : 0.f;
        att_s[tid] = ok ? att[b * NT + t] : 0.f;
    }

    // ---- per-thread constants: pack L_w rows to f16x2 as they arrive
    int a0 = 2 * tid;
    const float4* lp = (const float4*)(Lw + (long)a0 * NF);
    unsigned h0[16], h1[16];
#pragma unroll
    for (int i = 0; i < 8; ++i) {
        float4 wa = lp[i];
        float4 wb = lp[8 + i];
        h0[2 * i]     = pkrtz(wa.x, wa.y);
        h0[2 * i + 1] = pkrtz(wa.z, wa.w);
        h1[2 * i]     = pkrtz(wb.x, wb.y);
        h1[2 * i + 1] = pkrtz(wb.z, wb.w);
    }
    float c0 = pq[b * NA + a0]     + Lb[a0];
    float c1 = pq[b * NA + a0 + 1] + Lb[a0 + 1];
    float vx = vw[a0], vy = vw[a0 + 1];
    __syncthreads();

    // ---- conv phase: wave wv computes filters [8wv, 8wv+8) for tt = lane (all 64)
    {
        int tt  = lane;
        int fbu = wv * 8;
        float acc[8] = {0, 0, 0, 0, 0, 0, 0, 0};
#pragma unroll
        for (int k = 0; k < KW; ++k) {
            float x0 = cum_s[tt + k];
            float x1 = att_s[tt + k];
            const float4* A  = (const float4*)(cw_s + k * NF + fbu);
            const float4* Bv = (const float4*)(cw_s + (KW + k) * NF + fbu);
#pragma unroll
            for (int j = 0; j < 2; ++j) {
                float4 wa = A[j], wb = Bv[j];
                acc[4 * j + 0] = fmaf(x0, wa.x, fmaf(x1, wb.x, acc[4 * j + 0]));
                acc[4 * j + 1] = fmaf(x0, wa.y, fmaf(x1, wb.y, acc[4 * j + 1]));
                acc[4 * j + 2] = fmaf(x0, wa.z, fmaf(x1, wb.z, acc[4 * j + 2]));
                acc[4 * j + 3] = fmaf(x0, wa.w, fmaf(x1, wb.w, acc[4 * j + 3]));
            }
        }
        uint4 pk;
        pk.x = pkrtz(acc[0], acc[1]);
        pk.y = pkrtz(acc[2], acc[3]);
        pk.z = pkrtz(acc[4], acc[5]);
        pk.w = pkrtz(acc[6], acc[7]);
        *(uint4*)&cvsh[tt][wv * 4] = pk;
    }
    __syncthreads();

    // ---- main loop: two passes of 32 tt; per-thread 2 a's; f16 dot2
    const float* erow = enc + ((long)b * NT + t0) * NA + a0;
#pragma unroll 1
    for (int half = 0; half < 2; ++half) {
        float p32[32];
#pragma unroll
        for (int tt = 0; tt < 32; ++tt) {
            int gtt = half * 32 + tt;
            float2 e = *(const float2*)(erow + (long)gtt * NA);
            float x0[2] = {c0 + e.x, 0.f};
            float x1[2] = {c1 + e.y, 0.f};
#pragma unroll
            for (int q = 0; q < 4; ++q) {
                uint4 cv = *(const uint4*)&cvsh[gtt][4 * q];
                int p = q & 1;
                x0[p] = fdot2u(cv.x, h0[4 * q + 0], x0[p]);
                x0[p] = fdot2u(cv.y, h0[4 * q + 1], x0[p]);
                x0[p] = fdot2u(cv.z, h0[4 * q + 2], x0[p]);
                x0[p] = fdot2u(cv.w, h0[4 * q + 3], x0[p]);
                x1[p] = fdot2u(cv.x, h1[4 * q + 0], x1[p]);
                x1[p] = fdot2u(cv.y, h1[4 * q + 1], x1[p]);
                x1[p] = fdot2u(cv.z, h1[4 * q + 2], x1[p]);
                x1[p] = fdot2u(cv.w, h1[4 * q + 3], x1[p]);
            }
            p32[tt] = fast_tanh(x0[0] + x0[1]) * vx + fast_tanh(x1[0] + x1[1]) * vy;
        }

        // register butterfly transpose-reduce across lane bits 0..4
        {
            int len = 32;
#pragma unroll
            for (int m = 1; m <= 16; m <<= 1) {
                int hlen = len >> 1;
                bool up = (lane & m) != 0;
#pragma unroll
                for (int i = 0; i < 16; ++i) {
                    if (i < hlen) {
                        float send = up ? p32[i] : p32[i + hlen];
                        float keep = up ? p32[i + hlen] : p32[i];
                        p32[i] = keep + __shfl_xor(send, m, 64);
                    }
                }
                len = hlen;
            }
            float v = p32[0] + __shfl_xor(p32[0], 32, 64);
            int l = lane & 31;
            int tt = ((l & 1) << 4) | ((l & 2) << 2) | (l & 4) | ((l & 8) >> 2) | ((l & 16) >> 4);
            if (lane < 32) wred[wv][half * 32 + tt] = v;
        }
    }
    __syncthreads();
    if (tid < TC) {
        float u = wred[0][tid] + wred[1][tid] + wred[2][tid] + wred[3][tid];
        sout[b * NT + t0 + tid] = fast_sigmoid(u);
    }
}

// ---------------- kernel C: normalize with alpha recursion + mask (in place)
__global__ __launch_bounds__(256) void lsa_norm(
    const float* __restrict__ alpha, const int* __restrict__ plen,
    float* __restrict__ out)
{
    __shared__ float red[4];
    int tid = threadIdx.x;
    int b = blockIdx.x;
    int pl = plen[b];
    float w[4];
    float psum = 0.f;
#pragma unroll
    for (int j = 0; j < 4; ++j) {
        int t = tid + 256 * j;
        float s   = out[b * NT + t];
        float al  = alpha[b * NT + t];
        float am1 = (t >= 1) ? alpha[b * NT + t - 1] : 0.f;
        float am2 = (t >= 2) ? alpha[b * NT + t - 2] : 0.f;
        float val = (t < pl) ? (al + am1 + am2 + 1e-7f) * s : 0.f;
        w[j] = val;
        psum += val;
    }
#pragma unroll
    for (int m = 32; m >= 1; m >>= 1) psum += __shfl_xor(psum, m, 64);
    int lane = tid & 63, wid = tid >> 6;
    if (lane == 0) red[wid] = psum;
    __syncthreads();
    float total = red[0] + red[1] + red[2] + red[3];
    float inv = 1.0f / total;
#pragma unroll
    for (int j = 0; j < 4; ++j) {
        int t = tid + 256 * j;
        out[b * NT + t] = w[j] * inv;
    }
}

extern "C" void kernel_launch(void* const* d_in, const int* in_sizes, int n_in,
                              void* d_out, int out_size, void* d_ws, size_t ws_size,
                              hipStream_t stream)
{
    const float* enc   = (const float*)d_in[0];
    const float* query = (const float*)d_in[1];
    const float* cum   = (const float*)d_in[2];
    const float* att   = (const float*)d_in[3];
    const float* alpha = (const float*)d_in[4];
    const float* convw = (const float*)d_in[5];
    const float* Lw    = (const float*)d_in[6];
    const float* Lb    = (const float*)d_in[7];
    const float* Ww    = (const float*)d_in[8];
    const float* Wb    = (const float*)d_in[9];
    const float* vw    = (const float*)d_in[10];
    const int*   plen  = (const int*)d_in[12];

    float* pq  = (float*)d_ws;                       // 64*512 floats = 128 KB
    float* cwT = (float*)d_ws + NB * NA;             // 1984 floats
    float* sout = (float*)d_out;

    lsa_pq  <<<NB * 8,         256, 0, stream>>>(query, Ww, Wb, convw, pq, cwT);
    lsa_main<<<NB * (NT / TC), 256, 0, stream>>>(enc, cum, att, cwT, Lw, Lb, vw, pq, sout);
    lsa_norm<<<NB,             256, 0, stream>>>(alpha, plen, sout);
}